// Round 2
// baseline (1055.038 us; speedup 1.0000x reference)
//
#include <hip/hip_runtime.h>

// ---------------------------------------------------------------- utilities

__device__ __forceinline__ int rl(int v, int l) {
    return __builtin_amdgcn_readlane(v, l);
}
__device__ __forceinline__ float rlf(float v, int l) {
    return __int_as_float(__builtin_amdgcn_readlane(__float_as_int(v), l));
}

__global__ void count_kernel(const int* __restrict__ dst, int* __restrict__ cnt, int E) {
    int i = blockIdx.x * blockDim.x + threadIdx.x;
    if (i < E) atomicAdd(&cnt[dst[i]], 1);
}

// single-block exclusive scan of cnt -> roff; also emits dinv = rsqrt(cnt+1)
__global__ __launch_bounds__(1024) void scan_kernel(const int* __restrict__ cnt,
                                                    int* __restrict__ roff,
                                                    float* __restrict__ dinv, int n) {
    __shared__ int wsum[16];
    __shared__ int carry_s, total_s;
    int tid = threadIdx.x;
    int lane = tid & 63, w = tid >> 6;
    if (tid == 0) carry_s = 0;
    __syncthreads();
    for (int base = 0; base < n; base += 1024) {
        int i = base + tid;
        int v = (i < n) ? cnt[i] : 0;
        if (i < n) dinv[i] = rsqrtf((float)v + 1.0f);  // +1 self-loop
        int s = v;
#pragma unroll
        for (int d = 1; d < 64; d <<= 1) {
            int t = __shfl_up(s, d, 64);
            if (lane >= d) s += t;
        }
        if (lane == 63) wsum[w] = s;
        __syncthreads();
        if (w == 0) {
            int wv = (lane < 16) ? wsum[lane] : 0;
            int ss = wv;
#pragma unroll
            for (int d = 1; d < 16; d <<= 1) {
                int t = __shfl_up(ss, d, 64);
                if (lane >= d) ss += t;
            }
            if (lane < 16) wsum[lane] = ss - wv;   // exclusive wave offsets
            if (lane == 15) total_s = ss;          // chunk total
        }
        __syncthreads();
        int carry = carry_s;
        if (i < n) roff[i] = carry + wsum[w] + (s - v);
        __syncthreads();
        if (tid == 0) carry_s += total_s;
        __syncthreads();
    }
}

__global__ void scatter_kernel(const int* __restrict__ src, const int* __restrict__ dst,
                               const int* __restrict__ roff, int* __restrict__ cur,
                               const float* __restrict__ dinv,
                               int* __restrict__ es, float* __restrict__ en, int E) {
    int i = blockIdx.x * blockDim.x + threadIdx.x;
    if (i < E) {
        int d = dst[i], s = src[i];
        int p = roff[d] + atomicAdd(&cur[d], 1);
        es[p] = s;
        en[p] = dinv[s] * dinv[d];
    }
}

// ---------------------------------------------------------------- fp32 GEMM
// C[M x 256] = A[M x K] * B[K x 256], row-major. Tile 128x128xBK8, 256 thr, 8x8/thr.
// EPI: fused bias + relu epilogue.
template <int K, bool EPI>
__global__ __launch_bounds__(256) void sgemm_kernel(const float* __restrict__ A,
                                                    const float* __restrict__ B,
                                                    const float* __restrict__ bias,
                                                    float* __restrict__ C, int M) {
    __shared__ float As[8][128];
    __shared__ float Bs[8][128];
    int tid = threadIdx.x;
    int tx = tid & 15, ty = tid >> 4;
    int rowBase = blockIdx.x * 128;
    int colBase = blockIdx.y * 128;
    float acc[8][8] = {};
    int ar = rowBase + (tid >> 1);
    int ak = (tid & 1) * 4;
    int bk = tid >> 5;
    int bn = colBase + (tid & 31) * 4;

    for (int k0 = 0; k0 < K; k0 += 8) {
        float4 av = make_float4(0.f, 0.f, 0.f, 0.f);
        if (ar < M) av = *(const float4*)&A[(size_t)ar * K + k0 + ak];
        float4 bv = *(const float4*)&B[(size_t)(k0 + bk) * 256 + bn];
        __syncthreads();
        As[ak + 0][tid >> 1] = av.x;
        As[ak + 1][tid >> 1] = av.y;
        As[ak + 2][tid >> 1] = av.z;
        As[ak + 3][tid >> 1] = av.w;
        *(float4*)&Bs[bk][(tid & 31) * 4] = bv;
        __syncthreads();
#pragma unroll
        for (int kk = 0; kk < 8; ++kk) {
            float4 a0 = *(const float4*)&As[kk][ty * 8];
            float4 a1 = *(const float4*)&As[kk][ty * 8 + 4];
            float4 b0 = *(const float4*)&Bs[kk][tx * 8];
            float4 b1 = *(const float4*)&Bs[kk][tx * 8 + 4];
            float a[8] = {a0.x, a0.y, a0.z, a0.w, a1.x, a1.y, a1.z, a1.w};
            float b[8] = {b0.x, b0.y, b0.z, b0.w, b1.x, b1.y, b1.z, b1.w};
#pragma unroll
            for (int i = 0; i < 8; ++i)
#pragma unroll
                for (int j = 0; j < 8; ++j) acc[i][j] += a[i] * b[j];
        }
    }
    float bcol[8];
#pragma unroll
    for (int j = 0; j < 8; ++j) bcol[j] = EPI ? bias[colBase + tx * 8 + j] : 0.f;
#pragma unroll
    for (int i = 0; i < 8; ++i) {
        int r = rowBase + ty * 8 + i;
        if (r < M) {
            float o[8];
#pragma unroll
            for (int j = 0; j < 8; ++j)
                o[j] = EPI ? fmaxf(acc[i][j] + bcol[j], 0.f) : acc[i][j];
            *(float4*)&C[(size_t)r * 256 + colBase + tx * 8] =
                make_float4(o[0], o[1], o[2], o[3]);
            *(float4*)&C[(size_t)r * 256 + colBase + tx * 8 + 4] =
                make_float4(o[4], o[5], o[6], o[7]);
        }
    }
}

// ------------------------------------------------------------- aggregation
// One wave per destination node. Edge indices/norms are batch-loaded (64 per
// vector load) into registers and broadcast with readlane; row gathers are
// unrolled x4 for memory-level parallelism.

// D=128 (float2 per lane), no bias/relu (pre-GEMM aggregate of raw x)
__global__ __launch_bounds__(256) void agg128_kernel(const float* __restrict__ X,
                                                     const int* __restrict__ roff,
                                                     const int* __restrict__ cnt,
                                                     const int* __restrict__ es,
                                                     const float* __restrict__ en,
                                                     const float* __restrict__ dinv,
                                                     float* __restrict__ out, int n) {
    int wv = threadIdx.x >> 6, lane = threadIdx.x & 63;
    int node = blockIdx.x * 4 + wv;
    if (node >= n) return;
    const float2* Xr = (const float2*)X;
    float di = dinv[node];
    float sn = di * di;
    float2 acc = Xr[(size_t)node * 64 + lane];
    acc.x *= sn; acc.y *= sn;
    int beg = roff[node], m = cnt[node];
    for (int base = 0; base < m; base += 64) {
        int mm = min(64, m - base);
        int se = 0; float ne = 0.f;
        if (lane < mm) { se = es[beg + base + lane]; ne = en[beg + base + lane]; }
        int e = 0;
        for (; e + 4 <= mm; e += 4) {
            int s0 = rl(se, e), s1 = rl(se, e + 1), s2 = rl(se, e + 2), s3 = rl(se, e + 3);
            float n0 = rlf(ne, e), n1 = rlf(ne, e + 1), n2 = rlf(ne, e + 2), n3 = rlf(ne, e + 3);
            float2 h0 = Xr[(size_t)s0 * 64 + lane];
            float2 h1 = Xr[(size_t)s1 * 64 + lane];
            float2 h2 = Xr[(size_t)s2 * 64 + lane];
            float2 h3 = Xr[(size_t)s3 * 64 + lane];
            acc.x += h0.x * n0 + h1.x * n1 + h2.x * n2 + h3.x * n3;
            acc.y += h0.y * n0 + h1.y * n1 + h2.y * n2 + h3.y * n3;
        }
        for (; e < mm; ++e) {
            int s0 = rl(se, e);
            float n0 = rlf(ne, e);
            float2 h0 = Xr[(size_t)s0 * 64 + lane];
            acc.x += h0.x * n0;
            acc.y += h0.y * n0;
        }
    }
    ((float2*)out)[(size_t)node * 64 + lane] = acc;
}

// D=256 (float4 per lane), fused bias + relu (post-GEMM aggregate, layer 2)
__global__ __launch_bounds__(256) void agg256_kernel(const float* __restrict__ H,
                                                     const int* __restrict__ roff,
                                                     const int* __restrict__ cnt,
                                                     const int* __restrict__ es,
                                                     const float* __restrict__ en,
                                                     const float* __restrict__ dinv,
                                                     const float* __restrict__ bias,
                                                     float* __restrict__ out, int n) {
    int wv = threadIdx.x >> 6, lane = threadIdx.x & 63;
    int node = blockIdx.x * 4 + wv;
    if (node >= n) return;
    const float4* Hr = (const float4*)H;
    float di = dinv[node];
    float sn = di * di;
    float4 acc = Hr[(size_t)node * 64 + lane];
    acc.x *= sn; acc.y *= sn; acc.z *= sn; acc.w *= sn;
    int beg = roff[node], m = cnt[node];
    for (int base = 0; base < m; base += 64) {
        int mm = min(64, m - base);
        int se = 0; float ne = 0.f;
        if (lane < mm) { se = es[beg + base + lane]; ne = en[beg + base + lane]; }
        int e = 0;
        for (; e + 4 <= mm; e += 4) {
            int s0 = rl(se, e), s1 = rl(se, e + 1), s2 = rl(se, e + 2), s3 = rl(se, e + 3);
            float n0 = rlf(ne, e), n1 = rlf(ne, e + 1), n2 = rlf(ne, e + 2), n3 = rlf(ne, e + 3);
            float4 h0 = Hr[(size_t)s0 * 64 + lane];
            float4 h1 = Hr[(size_t)s1 * 64 + lane];
            float4 h2 = Hr[(size_t)s2 * 64 + lane];
            float4 h3 = Hr[(size_t)s3 * 64 + lane];
            acc.x += h0.x * n0 + h1.x * n1 + h2.x * n2 + h3.x * n3;
            acc.y += h0.y * n0 + h1.y * n1 + h2.y * n2 + h3.y * n3;
            acc.z += h0.z * n0 + h1.z * n1 + h2.z * n2 + h3.z * n3;
            acc.w += h0.w * n0 + h1.w * n1 + h2.w * n2 + h3.w * n3;
        }
        for (; e < mm; ++e) {
            int s0 = rl(se, e);
            float n0 = rlf(ne, e);
            float4 h0 = Hr[(size_t)s0 * 64 + lane];
            acc.x += h0.x * n0; acc.y += h0.y * n0;
            acc.z += h0.z * n0; acc.w += h0.w * n0;
        }
    }
    float4 bb = ((const float4*)bias)[lane];
    float4 o;
    o.x = fmaxf(acc.x + bb.x, 0.f);
    o.y = fmaxf(acc.y + bb.y, 0.f);
    o.z = fmaxf(acc.z + bb.z, 0.f);
    o.w = fmaxf(acc.w + bb.w, 0.f);
    ((float4*)out)[(size_t)node * 64 + lane] = o;
}

// ---------------------------------------------------------------- launcher

extern "C" void kernel_launch(void* const* d_in, const int* in_sizes, int n_in,
                              void* d_out, int out_size, void* d_ws, size_t ws_size,
                              hipStream_t stream) {
    const float* x  = (const float*)d_in[0];
    const int*   ei = (const int*)d_in[1];
    const float* W1 = (const float*)d_in[2];
    const float* b1 = (const float*)d_in[3];
    const float* W2 = (const float*)d_in[4];
    const float* b2 = (const float*)d_in[5];
    float* out = (float*)d_out;

    const int n = in_sizes[0] / 128;   // 100000 nodes
    const int E = in_sizes[1] / 2;     // 1.6M edges
    const int* src = ei;
    const int* dst = ei + E;

    // workspace carve-up (256B aligned); cnt+cur adjacent -> one memset
    size_t off = 0;
    auto alloc = [&](size_t bytes) {
        void* p = (char*)d_ws + off;
        off += (bytes + 255) & ~(size_t)255;
        return p;
    };
    int*   cnt  = (int*)alloc((size_t)n * 4);
    int*   cur  = (int*)alloc((size_t)n * 4);
    int*   roff = (int*)alloc((size_t)n * 4);
    float* dinv = (float*)alloc((size_t)n * 4);
    int*   es   = (int*)alloc((size_t)E * 4);
    float* en   = (float*)alloc((size_t)E * 4);
    float* buf  = (float*)alloc((size_t)n * 256 * 4);  // n x 128 (agg1) then n x 256 (gemm2)
    (void)ws_size;

    // ---- graph build
    hipMemsetAsync(cnt, 0, (size_t)(2 * n + 128) * 4, stream);  // cnt + cur (adjacent)
    count_kernel<<<(E + 255) / 256, 256, 0, stream>>>(dst, cnt, E);
    scan_kernel<<<1, 1024, 0, stream>>>(cnt, roff, dinv, n);
    scatter_kernel<<<(E + 255) / 256, 256, 0, stream>>>(src, dst, roff, cur, dinv, es, en, E);

    dim3 g1((n + 127) / 128, 2);
    // ---- layer 1: ax = Âx (128-dim); out = relu(ax @ W1 + b1)
    agg128_kernel<<<(n + 3) / 4, 256, 0, stream>>>(x, roff, cnt, es, en, dinv, buf, n);
    sgemm_kernel<128, true><<<g1, 256, 0, stream>>>(buf, W1, b1, out, n);

    // ---- layer 2: h2 = out @ W2 ; out = relu(Âh2 + b2)
    sgemm_kernel<256, false><<<g1, 256, 0, stream>>>(out, W2, nullptr, buf, n);
    agg256_kernel<<<(n + 3) / 4, 256, 0, stream>>>(buf, roff, cnt, es, en, dinv, b2, out, n);
}

// Round 3
// 1032.444 us; speedup vs baseline: 1.0219x; 1.0219x over previous
//
#include <hip/hip_runtime.h>

// ---------------------------------------------------------------- utilities

__device__ __forceinline__ int rl(int v, int l) {
    return __builtin_amdgcn_readlane(v, l);
}
__device__ __forceinline__ float rlf(float v, int l) {
    return __int_as_float(__builtin_amdgcn_readlane(__float_as_int(v), l));
}

__global__ void count_kernel(const int* __restrict__ dst, int* __restrict__ cnt, int E) {
    int i = blockIdx.x * blockDim.x + threadIdx.x;
    if (i < E) atomicAdd(&cnt[dst[i]], 1);
}

// single-block exclusive scan of cnt -> roff; also emits dinv = rsqrt(cnt+1)
__global__ __launch_bounds__(1024) void scan_kernel(const int* __restrict__ cnt,
                                                    int* __restrict__ roff,
                                                    float* __restrict__ dinv, int n) {
    __shared__ int wsum[16];
    __shared__ int carry_s, total_s;
    int tid = threadIdx.x;
    int lane = tid & 63, w = tid >> 6;
    if (tid == 0) carry_s = 0;
    __syncthreads();
    for (int base = 0; base < n; base += 1024) {
        int i = base + tid;
        int v = (i < n) ? cnt[i] : 0;
        if (i < n) dinv[i] = rsqrtf((float)v + 1.0f);  // +1 self-loop
        int s = v;
#pragma unroll
        for (int d = 1; d < 64; d <<= 1) {
            int t = __shfl_up(s, d, 64);
            if (lane >= d) s += t;
        }
        if (lane == 63) wsum[w] = s;
        __syncthreads();
        if (w == 0) {
            int wv = (lane < 16) ? wsum[lane] : 0;
            int ss = wv;
#pragma unroll
            for (int d = 1; d < 16; d <<= 1) {
                int t = __shfl_up(ss, d, 64);
                if (lane >= d) ss += t;
            }
            if (lane < 16) wsum[lane] = ss - wv;   // exclusive wave offsets
            if (lane == 15) total_s = ss;          // chunk total
        }
        __syncthreads();
        int carry = carry_s;
        if (i < n) roff[i] = carry + wsum[w] + (s - v);
        __syncthreads();
        if (tid == 0) carry_s += total_s;
        __syncthreads();
    }
}

__global__ void scatter_kernel(const int* __restrict__ src, const int* __restrict__ dst,
                               const int* __restrict__ roff, int* __restrict__ cur,
                               const float* __restrict__ dinv,
                               int* __restrict__ es, float* __restrict__ en, int E) {
    int i = blockIdx.x * blockDim.x + threadIdx.x;
    if (i < E) {
        int d = dst[i], s = src[i];
        int p = roff[d] + atomicAdd(&cur[d], 1);
        es[p] = s;
        en[p] = dinv[s] * dinv[d];
    }
}

// ---------------------------------------------------------------- fp32 GEMM
// C[M x 256] = A[M x K] * B[K x 256], row-major. Tile 128x128xBK8, 256 thr, 8x8/thr.
// At 121-154 TF this is ~98% of the fp32 vector roofline (no fp32 MFMA on CDNA4).
template <int K, bool EPI>
__global__ __launch_bounds__(256) void sgemm_kernel(const float* __restrict__ A,
                                                    const float* __restrict__ B,
                                                    const float* __restrict__ bias,
                                                    float* __restrict__ C, int M) {
    __shared__ float As[8][128];
    __shared__ float Bs[8][128];
    int tid = threadIdx.x;
    int tx = tid & 15, ty = tid >> 4;
    int rowBase = blockIdx.x * 128;
    int colBase = blockIdx.y * 128;
    float acc[8][8] = {};
    int ar = rowBase + (tid >> 1);
    int ak = (tid & 1) * 4;
    int bk = tid >> 5;
    int bn = colBase + (tid & 31) * 4;

    for (int k0 = 0; k0 < K; k0 += 8) {
        float4 av = make_float4(0.f, 0.f, 0.f, 0.f);
        if (ar < M) av = *(const float4*)&A[(size_t)ar * K + k0 + ak];
        float4 bv = *(const float4*)&B[(size_t)(k0 + bk) * 256 + bn];
        __syncthreads();
        As[ak + 0][tid >> 1] = av.x;
        As[ak + 1][tid >> 1] = av.y;
        As[ak + 2][tid >> 1] = av.z;
        As[ak + 3][tid >> 1] = av.w;
        *(float4*)&Bs[bk][(tid & 31) * 4] = bv;
        __syncthreads();
#pragma unroll
        for (int kk = 0; kk < 8; ++kk) {
            float4 a0 = *(const float4*)&As[kk][ty * 8];
            float4 a1 = *(const float4*)&As[kk][ty * 8 + 4];
            float4 b0 = *(const float4*)&Bs[kk][tx * 8];
            float4 b1 = *(const float4*)&Bs[kk][tx * 8 + 4];
            float a[8] = {a0.x, a0.y, a0.z, a0.w, a1.x, a1.y, a1.z, a1.w};
            float b[8] = {b0.x, b0.y, b0.z, b0.w, b1.x, b1.y, b1.z, b1.w};
#pragma unroll
            for (int i = 0; i < 8; ++i)
#pragma unroll
                for (int j = 0; j < 8; ++j) acc[i][j] += a[i] * b[j];
        }
    }
    float bcol[8];
#pragma unroll
    for (int j = 0; j < 8; ++j) bcol[j] = EPI ? bias[colBase + tx * 8 + j] : 0.f;
#pragma unroll
    for (int i = 0; i < 8; ++i) {
        int r = rowBase + ty * 8 + i;
        if (r < M) {
            float o[8];
#pragma unroll
            for (int j = 0; j < 8; ++j)
                o[j] = EPI ? fmaxf(acc[i][j] + bcol[j], 0.f) : acc[i][j];
            *(float4*)&C[(size_t)r * 256 + colBase + tx * 8] =
                make_float4(o[0], o[1], o[2], o[3]);
            *(float4*)&C[(size_t)r * 256 + colBase + tx * 8 + 4] =
                make_float4(o[4], o[5], o[6], o[7]);
        }
    }
}

// ------------------------------------------------------------- aggregation
// WPN waves per node, float2 (8B) per lane. WPN=1: D=128 rows (stride 64
// float2). WPN=2: D=256 rows (stride 128 float2), each wave owns 128 channels.
// Edge index/norm batches (64) are vector-loaded then readlane-broadcast
// (lands in SGPRs); row gathers manually unrolled x8 for 8 loads in flight.
template <int WPN, int STRIDE_F2, bool EPI>
__global__ __launch_bounds__(256) void agg_kernel(const float2* __restrict__ H,
                                                  const int* __restrict__ roff,
                                                  const int* __restrict__ cnt,
                                                  const int* __restrict__ es,
                                                  const float* __restrict__ en,
                                                  const float* __restrict__ dinv,
                                                  const float* __restrict__ bias,
                                                  float2* __restrict__ out, int n) {
    int wv = threadIdx.x >> 6, lane = threadIdx.x & 63;
    int gw = blockIdx.x * 4 + wv;
    int node = (WPN == 1) ? gw : (gw >> 1);
    int half = (WPN == 1) ? 0 : (gw & 1);
    if (node >= n) return;
    int offF2 = half * 64 + lane;

    float di = dinv[node];
    float sn = di * di;  // self-loop norm
    float2 acc = H[(size_t)node * STRIDE_F2 + offF2];
    acc.x *= sn; acc.y *= sn;

    int beg = roff[node], m = cnt[node];
    for (int base = 0; base < m; base += 64) {
        int mm = min(64, m - base);
        int se = 0; float ne = 0.f;
        if (lane < mm) { se = es[beg + base + lane]; ne = en[beg + base + lane]; }
        int e = 0;
        for (; e + 8 <= mm; e += 8) {
            int s0 = rl(se, e + 0), s1 = rl(se, e + 1);
            int s2 = rl(se, e + 2), s3 = rl(se, e + 3);
            int s4 = rl(se, e + 4), s5 = rl(se, e + 5);
            int s6 = rl(se, e + 6), s7 = rl(se, e + 7);
            float n0 = rlf(ne, e + 0), n1 = rlf(ne, e + 1);
            float n2 = rlf(ne, e + 2), n3 = rlf(ne, e + 3);
            float n4 = rlf(ne, e + 4), n5 = rlf(ne, e + 5);
            float n6 = rlf(ne, e + 6), n7 = rlf(ne, e + 7);
            float2 h0 = H[(size_t)s0 * STRIDE_F2 + offF2];
            float2 h1 = H[(size_t)s1 * STRIDE_F2 + offF2];
            float2 h2 = H[(size_t)s2 * STRIDE_F2 + offF2];
            float2 h3 = H[(size_t)s3 * STRIDE_F2 + offF2];
            float2 h4 = H[(size_t)s4 * STRIDE_F2 + offF2];
            float2 h5 = H[(size_t)s5 * STRIDE_F2 + offF2];
            float2 h6 = H[(size_t)s6 * STRIDE_F2 + offF2];
            float2 h7 = H[(size_t)s7 * STRIDE_F2 + offF2];
            acc.x += h0.x * n0 + h1.x * n1 + h2.x * n2 + h3.x * n3;
            acc.y += h0.y * n0 + h1.y * n1 + h2.y * n2 + h3.y * n3;
            acc.x += h4.x * n4 + h5.x * n5 + h6.x * n6 + h7.x * n7;
            acc.y += h4.y * n4 + h5.y * n5 + h6.y * n6 + h7.y * n7;
        }
        for (; e < mm; ++e) {
            int s0 = rl(se, e);
            float n0 = rlf(ne, e);
            float2 h0 = H[(size_t)s0 * STRIDE_F2 + offF2];
            acc.x += h0.x * n0;
            acc.y += h0.y * n0;
        }
    }
    if (EPI) {
        float2 bb = ((const float2*)bias)[offF2];
        acc.x = fmaxf(acc.x + bb.x, 0.f);
        acc.y = fmaxf(acc.y + bb.y, 0.f);
    }
    out[(size_t)node * STRIDE_F2 + offF2] = acc;
}

// ---------------------------------------------------------------- launcher

extern "C" void kernel_launch(void* const* d_in, const int* in_sizes, int n_in,
                              void* d_out, int out_size, void* d_ws, size_t ws_size,
                              hipStream_t stream) {
    const float* x  = (const float*)d_in[0];
    const int*   ei = (const int*)d_in[1];
    const float* W1 = (const float*)d_in[2];
    const float* b1 = (const float*)d_in[3];
    const float* W2 = (const float*)d_in[4];
    const float* b2 = (const float*)d_in[5];
    float* out = (float*)d_out;

    const int n = in_sizes[0] / 128;   // 100000 nodes
    const int E = in_sizes[1] / 2;     // 1.6M edges
    const int* src = ei;
    const int* dst = ei + E;

    // workspace carve-up (256B aligned); cnt+cur adjacent -> one memset
    size_t off = 0;
    auto alloc = [&](size_t bytes) {
        void* p = (char*)d_ws + off;
        off += (bytes + 255) & ~(size_t)255;
        return p;
    };
    int*   cnt  = (int*)alloc((size_t)n * 4);
    int*   cur  = (int*)alloc((size_t)n * 4);
    int*   roff = (int*)alloc((size_t)n * 4);
    float* dinv = (float*)alloc((size_t)n * 4);
    int*   es   = (int*)alloc((size_t)E * 4);
    float* en   = (float*)alloc((size_t)E * 4);
    float* buf  = (float*)alloc((size_t)n * 256 * 4);  // n x 128 (agg1) then n x 256 (gemm2)
    (void)ws_size;

    // ---- graph build
    hipMemsetAsync(cnt, 0, (size_t)(2 * n + 128) * 4, stream);  // cnt + cur (adjacent)
    count_kernel<<<(E + 255) / 256, 256, 0, stream>>>(dst, cnt, E);
    scan_kernel<<<1, 1024, 0, stream>>>(cnt, roff, dinv, n);
    scatter_kernel<<<(E + 255) / 256, 256, 0, stream>>>(src, dst, roff, cur, dinv, es, en, E);

    dim3 g1((n + 127) / 128, 2);
    // ---- layer 1: ax = Âx (128-dim); out = relu(ax @ W1 + b1)
    agg_kernel<1, 64, false><<<(n + 3) / 4, 256, 0, stream>>>(
        (const float2*)x, roff, cnt, es, en, dinv, nullptr, (float2*)buf, n);
    sgemm_kernel<128, true><<<g1, 256, 0, stream>>>(buf, W1, b1, out, n);

    // ---- layer 2: h2 = out @ W2 ; out = relu(Âh2 + b2)
    sgemm_kernel<256, false><<<g1, 256, 0, stream>>>(out, W2, nullptr, buf, n);
    agg_kernel<2, 128, true><<<(2 * n + 3) / 4, 256, 0, stream>>>(
        (const float2*)buf, roff, cnt, es, en, dinv, b2, (float2*)out, n);
}

// Round 4
// 921.977 us; speedup vs baseline: 1.1443x; 1.1198x over previous
//
#include <hip/hip_runtime.h>

typedef unsigned int uint32;

// ---------------------------------------------------------------- utilities

__device__ __forceinline__ int rl(int v, int l) {
    return __builtin_amdgcn_readlane(v, l);
}
__device__ __forceinline__ float rlf(int v, int l) {
    return __int_as_float(__builtin_amdgcn_readlane(v, l));
}
__device__ __forceinline__ uint32 f2bf(float x) {  // RNE f32 -> bf16 (low 16 bits)
    uint32 u = __float_as_uint(x);
    return (u + 0x7fffu + ((u >> 16) & 1u)) >> 16;
}
__device__ __forceinline__ float bfLo(uint32 u) { return __uint_as_float(u << 16); }
__device__ __forceinline__ float bfHi(uint32 u) { return __uint_as_float(u & 0xffff0000u); }

__global__ void count_kernel(const int* __restrict__ dst, int* __restrict__ cnt, int E) {
    int i = blockIdx.x * blockDim.x + threadIdx.x;
    if (i < E) atomicAdd(&cnt[dst[i]], 1);
}

// single-block exclusive scan of cnt -> roff; also emits dinv = rsqrt(cnt+1)
__global__ __launch_bounds__(1024) void scan_kernel(const int* __restrict__ cnt,
                                                    int* __restrict__ roff,
                                                    float* __restrict__ dinv, int n) {
    __shared__ int wsum[16];
    __shared__ int carry_s, total_s;
    int tid = threadIdx.x;
    int lane = tid & 63, w = tid >> 6;
    if (tid == 0) carry_s = 0;
    __syncthreads();
    for (int base = 0; base < n; base += 1024) {
        int i = base + tid;
        int v = (i < n) ? cnt[i] : 0;
        if (i < n) dinv[i] = rsqrtf((float)v + 1.0f);  // +1 self-loop
        int s = v;
#pragma unroll
        for (int d = 1; d < 64; d <<= 1) {
            int t = __shfl_up(s, d, 64);
            if (lane >= d) s += t;
        }
        if (lane == 63) wsum[w] = s;
        __syncthreads();
        if (w == 0) {
            int wv = (lane < 16) ? wsum[lane] : 0;
            int ss = wv;
#pragma unroll
            for (int d = 1; d < 16; d <<= 1) {
                int t = __shfl_up(ss, d, 64);
                if (lane >= d) ss += t;
            }
            if (lane < 16) wsum[lane] = ss - wv;   // exclusive wave offsets
            if (lane == 15) total_s = ss;          // chunk total
        }
        __syncthreads();
        int carry = carry_s;
        if (i < n) roff[i] = carry + wsum[w] + (s - v);
        __syncthreads();
        if (tid == 0) carry_s += total_s;
        __syncthreads();
    }
}

// emits interleaved (src, norm) pairs per edge slot
__global__ void scatter_kernel(const int* __restrict__ src, const int* __restrict__ dst,
                               const int* __restrict__ roff, int* __restrict__ cur,
                               const float* __restrict__ dinv,
                               int2* __restrict__ ese, int E) {
    int i = blockIdx.x * blockDim.x + threadIdx.x;
    if (i < E) {
        int d = dst[i], s = src[i];
        int p = roff[d] + atomicAdd(&cur[d], 1);
        ese[p] = make_int2(s, __float_as_int(dinv[s] * dinv[d]));
    }
}

// ---------------------------------------------------------------- fp32 GEMM
// C[M x 256] = A[M x K] * B[K x 256], row-major. Tile 128x128xBK8, 256 thr, 8x8/thr.
// At 121-154 TF this is ~98% of the fp32 vector roofline (no fp32 MFMA on CDNA4).
// OUT_MODE: 0 = raw fp32, 1 = fp32 bias+relu, 2 = raw bf16 (packed 2/uint)
template <int K, int OUT_MODE>
__global__ __launch_bounds__(256) void sgemm_kernel(const float* __restrict__ A,
                                                    const float* __restrict__ B,
                                                    const float* __restrict__ bias,
                                                    float* __restrict__ C, int M) {
    __shared__ float As[8][128];
    __shared__ float Bs[8][128];
    int tid = threadIdx.x;
    int tx = tid & 15, ty = tid >> 4;
    int rowBase = blockIdx.x * 128;
    int colBase = blockIdx.y * 128;
    float acc[8][8] = {};
    int ar = rowBase + (tid >> 1);
    int ak = (tid & 1) * 4;
    int bk = tid >> 5;
    int bn = colBase + (tid & 31) * 4;

    for (int k0 = 0; k0 < K; k0 += 8) {
        float4 av = make_float4(0.f, 0.f, 0.f, 0.f);
        if (ar < M) av = *(const float4*)&A[(size_t)ar * K + k0 + ak];
        float4 bv = *(const float4*)&B[(size_t)(k0 + bk) * 256 + bn];
        __syncthreads();
        As[ak + 0][tid >> 1] = av.x;
        As[ak + 1][tid >> 1] = av.y;
        As[ak + 2][tid >> 1] = av.z;
        As[ak + 3][tid >> 1] = av.w;
        *(float4*)&Bs[bk][(tid & 31) * 4] = bv;
        __syncthreads();
#pragma unroll
        for (int kk = 0; kk < 8; ++kk) {
            float4 a0 = *(const float4*)&As[kk][ty * 8];
            float4 a1 = *(const float4*)&As[kk][ty * 8 + 4];
            float4 b0 = *(const float4*)&Bs[kk][tx * 8];
            float4 b1 = *(const float4*)&Bs[kk][tx * 8 + 4];
            float a[8] = {a0.x, a0.y, a0.z, a0.w, a1.x, a1.y, a1.z, a1.w};
            float b[8] = {b0.x, b0.y, b0.z, b0.w, b1.x, b1.y, b1.z, b1.w};
#pragma unroll
            for (int i = 0; i < 8; ++i)
#pragma unroll
                for (int j = 0; j < 8; ++j) acc[i][j] += a[i] * b[j];
        }
    }
    float bcol[8];
#pragma unroll
    for (int j = 0; j < 8; ++j) bcol[j] = (OUT_MODE == 1) ? bias[colBase + tx * 8 + j] : 0.f;
#pragma unroll
    for (int i = 0; i < 8; ++i) {
        int r = rowBase + ty * 8 + i;
        if (r < M) {
            if (OUT_MODE == 2) {
                uint32* Cb = (uint32*)C;  // bf16 pairs, row stride 128 uints
                uint4 pk;
                pk.x = f2bf(acc[i][0]) | (f2bf(acc[i][1]) << 16);
                pk.y = f2bf(acc[i][2]) | (f2bf(acc[i][3]) << 16);
                pk.z = f2bf(acc[i][4]) | (f2bf(acc[i][5]) << 16);
                pk.w = f2bf(acc[i][6]) | (f2bf(acc[i][7]) << 16);
                *(uint4*)&Cb[(size_t)r * 128 + (colBase >> 1) + tx * 4] = pk;
            } else {
                float o[8];
#pragma unroll
                for (int j = 0; j < 8; ++j)
                    o[j] = (OUT_MODE == 1) ? fmaxf(acc[i][j] + bcol[j], 0.f) : acc[i][j];
                *(float4*)&C[(size_t)r * 256 + colBase + tx * 8] =
                    make_float4(o[0], o[1], o[2], o[3]);
                *(float4*)&C[(size_t)r * 256 + colBase + tx * 8 + 4] =
                    make_float4(o[4], o[5], o[6], o[7]);
            }
        }
    }
}

// ------------------------------------------------------------- aggregation
// Layer 1: one wave per node, fp32 float2/lane over D=128 rows of x.
// Edge (src,norm) batches (64 int2) vector-loaded then readlane-broadcast;
// row gathers unrolled x8 for 8 loads in flight.
__global__ __launch_bounds__(256) void agg1_kernel(const float2* __restrict__ X,
                                                   const int* __restrict__ roff,
                                                   const int* __restrict__ cnt,
                                                   const int2* __restrict__ ese,
                                                   const float* __restrict__ dinv,
                                                   float2* __restrict__ out, int n) {
    int wv = threadIdx.x >> 6, lane = threadIdx.x & 63;
    int node = blockIdx.x * 4 + wv;
    if (node >= n) return;

    float di = dinv[node];
    float sn = di * di;  // self-loop norm
    float2 acc = X[(size_t)node * 64 + lane];
    acc.x *= sn; acc.y *= sn;

    int beg = roff[node], m = cnt[node];
    for (int base = 0; base < m; base += 64) {
        int mm = min(64, m - base);
        int2 ev = make_int2(0, 0);
        if (lane < mm) ev = ese[beg + base + lane];
        int e = 0;
        for (; e + 8 <= mm; e += 8) {
            int s0 = rl(ev.x, e + 0), s1 = rl(ev.x, e + 1);
            int s2 = rl(ev.x, e + 2), s3 = rl(ev.x, e + 3);
            int s4 = rl(ev.x, e + 4), s5 = rl(ev.x, e + 5);
            int s6 = rl(ev.x, e + 6), s7 = rl(ev.x, e + 7);
            float n0 = rlf(ev.y, e + 0), n1 = rlf(ev.y, e + 1);
            float n2 = rlf(ev.y, e + 2), n3 = rlf(ev.y, e + 3);
            float n4 = rlf(ev.y, e + 4), n5 = rlf(ev.y, e + 5);
            float n6 = rlf(ev.y, e + 6), n7 = rlf(ev.y, e + 7);
            float2 h0 = X[(size_t)s0 * 64 + lane];
            float2 h1 = X[(size_t)s1 * 64 + lane];
            float2 h2 = X[(size_t)s2 * 64 + lane];
            float2 h3 = X[(size_t)s3 * 64 + lane];
            float2 h4 = X[(size_t)s4 * 64 + lane];
            float2 h5 = X[(size_t)s5 * 64 + lane];
            float2 h6 = X[(size_t)s6 * 64 + lane];
            float2 h7 = X[(size_t)s7 * 64 + lane];
            acc.x += h0.x * n0 + h1.x * n1 + h2.x * n2 + h3.x * n3;
            acc.y += h0.y * n0 + h1.y * n1 + h2.y * n2 + h3.y * n3;
            acc.x += h4.x * n4 + h5.x * n5 + h6.x * n6 + h7.x * n7;
            acc.y += h4.y * n4 + h5.y * n5 + h6.y * n6 + h7.y * n7;
        }
        for (; e < mm; ++e) {
            int s0 = rl(ev.x, e);
            float n0 = rlf(ev.y, e);
            float2 h0 = X[(size_t)s0 * 64 + lane];
            acc.x += h0.x * n0;
            acc.y += h0.y * n0;
        }
    }
    out[(size_t)node * 64 + lane] = acc;
}

// Layer 2: 2 waves per node, bf16 payload (1 uint = 2 channels per lane),
// fp32 accumulate, fused bias + relu, fp32 output.
__global__ __launch_bounds__(256) void agg2_kernel(const uint32* __restrict__ Hbf,
                                                   const int* __restrict__ roff,
                                                   const int* __restrict__ cnt,
                                                   const int2* __restrict__ ese,
                                                   const float* __restrict__ dinv,
                                                   const float* __restrict__ bias,
                                                   float2* __restrict__ out, int n) {
    int wv = threadIdx.x >> 6, lane = threadIdx.x & 63;
    int gw = blockIdx.x * 4 + wv;
    int node = gw >> 1, half = gw & 1;
    if (node >= n) return;
    int offU = half * 64 + lane;  // uint offset within row (128 uints/row)

    float di = dinv[node];
    float sn = di * di;
    uint32 sg = Hbf[(size_t)node * 128 + offU];
    float2 acc;
    acc.x = bfLo(sg) * sn;
    acc.y = bfHi(sg) * sn;

    int beg = roff[node], m = cnt[node];
    for (int base = 0; base < m; base += 64) {
        int mm = min(64, m - base);
        int2 ev = make_int2(0, 0);
        if (lane < mm) ev = ese[beg + base + lane];
        int e = 0;
        for (; e + 8 <= mm; e += 8) {
            int s0 = rl(ev.x, e + 0), s1 = rl(ev.x, e + 1);
            int s2 = rl(ev.x, e + 2), s3 = rl(ev.x, e + 3);
            int s4 = rl(ev.x, e + 4), s5 = rl(ev.x, e + 5);
            int s6 = rl(ev.x, e + 6), s7 = rl(ev.x, e + 7);
            float n0 = rlf(ev.y, e + 0), n1 = rlf(ev.y, e + 1);
            float n2 = rlf(ev.y, e + 2), n3 = rlf(ev.y, e + 3);
            float n4 = rlf(ev.y, e + 4), n5 = rlf(ev.y, e + 5);
            float n6 = rlf(ev.y, e + 6), n7 = rlf(ev.y, e + 7);
            uint32 g0 = Hbf[(size_t)s0 * 128 + offU];
            uint32 g1 = Hbf[(size_t)s1 * 128 + offU];
            uint32 g2 = Hbf[(size_t)s2 * 128 + offU];
            uint32 g3 = Hbf[(size_t)s3 * 128 + offU];
            uint32 g4 = Hbf[(size_t)s4 * 128 + offU];
            uint32 g5 = Hbf[(size_t)s5 * 128 + offU];
            uint32 g6 = Hbf[(size_t)s6 * 128 + offU];
            uint32 g7 = Hbf[(size_t)s7 * 128 + offU];
            acc.x += bfLo(g0) * n0 + bfLo(g1) * n1 + bfLo(g2) * n2 + bfLo(g3) * n3;
            acc.y += bfHi(g0) * n0 + bfHi(g1) * n1 + bfHi(g2) * n2 + bfHi(g3) * n3;
            acc.x += bfLo(g4) * n4 + bfLo(g5) * n5 + bfLo(g6) * n6 + bfLo(g7) * n7;
            acc.y += bfHi(g4) * n4 + bfHi(g5) * n5 + bfHi(g6) * n6 + bfHi(g7) * n7;
        }
        for (; e < mm; ++e) {
            int s0 = rl(ev.x, e);
            float n0 = rlf(ev.y, e);
            uint32 g0 = Hbf[(size_t)s0 * 128 + offU];
            acc.x += bfLo(g0) * n0;
            acc.y += bfHi(g0) * n0;
        }
    }
    float2 bb = ((const float2*)bias)[offU];
    acc.x = fmaxf(acc.x + bb.x, 0.f);
    acc.y = fmaxf(acc.y + bb.y, 0.f);
    out[(size_t)node * 128 + offU] = acc;
}

// ---------------------------------------------------------------- launcher

extern "C" void kernel_launch(void* const* d_in, const int* in_sizes, int n_in,
                              void* d_out, int out_size, void* d_ws, size_t ws_size,
                              hipStream_t stream) {
    const float* x  = (const float*)d_in[0];
    const int*   ei = (const int*)d_in[1];
    const float* W1 = (const float*)d_in[2];
    const float* b1 = (const float*)d_in[3];
    const float* W2 = (const float*)d_in[4];
    const float* b2 = (const float*)d_in[5];
    float* out = (float*)d_out;

    const int n = in_sizes[0] / 128;   // 100000 nodes
    const int E = in_sizes[1] / 2;     // 1.6M edges
    const int* src = ei;
    const int* dst = ei + E;

    // workspace carve-up (256B aligned); cnt+cur adjacent -> one memset
    size_t off = 0;
    auto alloc = [&](size_t bytes) {
        void* p = (char*)d_ws + off;
        off += (bytes + 255) & ~(size_t)255;
        return p;
    };
    int*   cnt  = (int*)alloc((size_t)n * 4);
    int*   cur  = (int*)alloc((size_t)n * 4);
    int*   roff = (int*)alloc((size_t)n * 4);
    float* dinv = (float*)alloc((size_t)n * 4);
    int2*  ese  = (int2*)alloc((size_t)E * 8);
    // shared buffer: agg1 output (n x 128 fp32 = 51.2MB), then h2-bf16 (n x 256 bf16 = 51.2MB)
    float* buf  = (float*)alloc((size_t)n * 128 * 4);
    (void)ws_size;

    // ---- graph build
    hipMemsetAsync(cnt, 0, (size_t)(2 * n + 128) * 4, stream);  // cnt + cur (adjacent)
    count_kernel<<<(E + 255) / 256, 256, 0, stream>>>(dst, cnt, E);
    scan_kernel<<<1, 1024, 0, stream>>>(cnt, roff, dinv, n);
    scatter_kernel<<<(E + 255) / 256, 256, 0, stream>>>(src, dst, roff, cur, dinv, ese, E);

    dim3 g1((n + 127) / 128, 2);
    // ---- layer 1: ax = Âx (128-dim); out = relu(ax @ W1 + b1)
    agg1_kernel<<<(n + 3) / 4, 256, 0, stream>>>(
        (const float2*)x, roff, cnt, ese, dinv, (float2*)buf, n);
    sgemm_kernel<128, 1><<<g1, 256, 0, stream>>>(buf, W1, b1, out, n);

    // ---- layer 2: h2 = bf16(out @ W2) ; out = relu(Â h2 + b2)
    sgemm_kernel<256, 2><<<g1, 256, 0, stream>>>(out, W2, nullptr, buf, n);
    agg2_kernel<<<(2 * n + 3) / 4, 256, 0, stream>>>(
        (const uint32*)buf, roff, cnt, ese, dinv, b2, (float2*)out, n);
}